// Round 6
// baseline (422.454 us; speedup 1.0000x reference)
//
#include <hip/hip_runtime.h>
#include <stdint.h>

// FusedGCNLayer: out = segment_sum(vals * (x @ W^T)[col], row)
// N=65536, E=524288, F=EMB=512.
// Budget model (4 measured rounds): fixed harness overhead ~145us; kernel-sum is the target.
// Pipeline: (1) prep: conv w->bf16 + zero cnt
//           (2) fill_edges: bin edges by dest row (round-0 proven shape, ~35us)
//           (3) gemm_fused BN=256: 40KB LDS -> 4 blocks/CU (was 72KB/2 blocks -> 99us),
//               x read twice, XCD-paired swizzle keeps both n-tiles of an m on one L2
//           (4) rowsum: one wave/row batched gathers (round-0 proven, ~99us @ 4.1TB/s wall)

#define N_NODES 65536
#define N_EDGES 524288
#define FEAT    512
#define EMB     512
#define CAP     64

typedef short  short8  __attribute__((ext_vector_type(8)));
typedef float  floatx4 __attribute__((ext_vector_type(4)));
typedef unsigned int uintx2 __attribute__((ext_vector_type(2)));

__device__ __forceinline__ unsigned short f2bf(float f) {
    unsigned int u = __float_as_uint(f);
    u += 0x7FFFu + ((u >> 16) & 1u);   // RNE
    return (unsigned short)(u >> 16);
}
__device__ __forceinline__ float bf2f_lo(unsigned int u){ return __uint_as_float(u << 16); }
__device__ __forceinline__ float bf2f_hi(unsigned int u){ return __uint_as_float(u & 0xffff0000u); }

typedef __attribute__((address_space(1))) const void* gas_vp;
typedef __attribute__((address_space(3))) void*       las_vp;
#define GLDS16(g, l) __builtin_amdgcn_global_load_lds((gas_vp)(const void*)(g), (las_vp)(void*)(l), 16, 0, 0)

// ---------------- prep: convert w (0.5 MB) to bf16 + zero cnt, one dispatch ----------------
__global__ __launch_bounds__(256)
void prep(const float* __restrict__ w, unsigned short* __restrict__ wb,
          int* __restrict__ cnt)
{
    size_t i = (size_t)blockIdx.x * 256 + threadIdx.x;   // 128 blocks * 256 = 32768 threads
    size_t j = i * 8;
    floatx4 a = *(const floatx4*)&w[j];
    floatx4 b = *(const floatx4*)&w[j + 4];
    ushort4 lo, hi;
    lo.x = f2bf(a.x); lo.y = f2bf(a.y); lo.z = f2bf(a.z); lo.w = f2bf(a.w);
    hi.x = f2bf(b.x); hi.y = f2bf(b.y); hi.z = f2bf(b.z); hi.w = f2bf(b.w);
    *(ushort4*)&wb[j]     = lo;
    *(ushort4*)&wb[j + 4] = hi;
    int2 z; z.x = 0; z.y = 0;
    *(int2*)&cnt[i * 2] = z;   // 65536 ints
}

// ---------------- bin edges by destination row (round-0 proven shape) ----------------
__global__ __launch_bounds__(256)
void fill_edges(const int* __restrict__ row, const int* __restrict__ col,
                const float* __restrict__ vals, int* __restrict__ cnt,
                uintx2* __restrict__ ebuf)
{
    int e = blockIdx.x * 256 + threadIdx.x;
    int   r = __builtin_nontemporal_load(&row[e]);
    int   c = __builtin_nontemporal_load(&col[e]);
    float v = __builtin_nontemporal_load(&vals[e]);
    int slot = atomicAdd(&cnt[r], 1);
    if (slot < CAP) {
        uintx2 ev; ev.x = (unsigned)c; ev.y = __float_as_uint(v);
        ebuf[r * CAP + slot] = ev;
    }
}

// ---------------- fused GEMM: BM=64 x BN=256, 40KB LDS -> 4 blocks/CU ----------------
// 512 threads = 8 waves; wave w owns output cols [n0 + w*32, n0 + w*32 + 32).
// A (x tile): fp32 global -> regs -> f2bf -> swizzled ds_write (proven round-3 path).
// B (wb):     global_load_lds width-16, pre-swizzled source, linear LDS dest.
// Swizzle: same-m n-pairs land on the same XCD so x rows are fetched once per XCD.
__global__ __launch_bounds__(512, 8)
void gemm_fused(const float* __restrict__ x, const unsigned short* __restrict__ wb,
                unsigned short* __restrict__ h)
{
    __shared__ unsigned short As[64 * 64];    //  8 KB
    __shared__ unsigned short Bs[256 * 64];   // 32 KB

    // XCD-pairing swizzle: blocks bid and bid+8 (same XCD under round-robin) form the
    // (n=0, n=1) pair of one m-tile. lid = (bid%8)*256 + bid/8; 2048 % 8 == 0 (bijective).
    const int bid = blockIdx.x;
    const int lid = (bid & 7) * 256 + (bid >> 3);
    const int m0  = (lid >> 1) * 64;
    const int n0  = (lid & 1) * 256;

    const int t    = threadIdx.x;      // 0..511
    const int lane = t & 63;
    const int wave = t >> 6;           // 0..7 -> 32-col sub-block
    const int l15  = lane & 15;
    const int lq   = lane >> 4;

    const int r8 = t >> 3;             // 0..63 (staging row)
    const int c8 = t & 7;              // 16B chunk index

    floatx4 acc[4][2];
    #pragma unroll
    for (int i = 0; i < 4; i++)
        #pragma unroll
        for (int j = 0; j < 2; j++) acc[i][j] = (floatx4){0.f, 0.f, 0.f, 0.f};

    // prefetch K-step 0 of A into regs
    float4 xa, xb_;
    {
        const float* px = &x[(size_t)(m0 + r8) * FEAT + c8 * 8];
        xa  = *(const float4*)px;
        xb_ = *(const float4*)(px + 4);
    }

    for (int kb = 0; kb < FEAT; kb += 64) {
        // stage Bs: 256 w-rows [n0, n0+256), 64-wide K slab, pre-swizzled global source
        #pragma unroll
        for (int p = 0; p < 4; p++) {
            int brow = p * 64 + r8;
            int lc   = c8 ^ (r8 & 7);                 // brow&7 == r8&7 (p*64 % 8 == 0)
            GLDS16(&wb[(size_t)(n0 + brow) * FEAT + kb + lc * 8], &Bs[brow * 64 + c8 * 8]);
        }
        // convert prefetched A regs -> swizzled LDS write
        {
            short8 v;
            v[0] = (short)f2bf(xa.x);  v[1] = (short)f2bf(xa.y);
            v[2] = (short)f2bf(xa.z);  v[3] = (short)f2bf(xa.w);
            v[4] = (short)f2bf(xb_.x); v[5] = (short)f2bf(xb_.y);
            v[6] = (short)f2bf(xb_.z); v[7] = (short)f2bf(xb_.w);
            *(short8*)&As[r8 * 64 + (c8 ^ (r8 & 7)) * 8] = v;
        }
        __syncthreads();

        // issue next K-step's x loads; latency hides under MFMA phase
        if (kb + 64 < FEAT) {
            const float* px = &x[(size_t)(m0 + r8) * FEAT + (kb + 64) + c8 * 8];
            xa  = *(const float4*)px;
            xb_ = *(const float4*)(px + 4);
        }

        #pragma unroll
        for (int kk = 0; kk < 2; kk++) {
            short8 af[4], bfr[2];
            #pragma unroll
            for (int mt = 0; mt < 4; mt++) {
                int r  = mt * 16 + l15;
                int pc = (kk * 4 + lq) ^ (r & 7);
                af[mt] = *(const short8*)&As[r * 64 + pc * 8];
            }
            #pragma unroll
            for (int nt = 0; nt < 2; nt++) {
                int r  = wave * 32 + nt * 16 + l15;
                int pc = (kk * 4 + lq) ^ (r & 7);
                bfr[nt] = *(const short8*)&Bs[r * 64 + pc * 8];
            }
            #pragma unroll
            for (int mt = 0; mt < 4; mt++)
                #pragma unroll
                for (int nt = 0; nt < 2; nt++)
                    acc[mt][nt] = __builtin_amdgcn_mfma_f32_16x16x32_bf16(
                        af[mt], bfr[nt], acc[mt][nt], 0, 0, 0);
        }
        __syncthreads();
    }

    #pragma unroll
    for (int mt = 0; mt < 4; mt++)
        #pragma unroll
        for (int nt = 0; nt < 2; nt++)
            #pragma unroll
            for (int r = 0; r < 4; r++) {
                int orow = m0 + mt * 16 + lq * 4 + r;
                int ocol = n0 + wave * 32 + nt * 16 + l15;
                h[(size_t)orow * EMB + ocol] = f2bf(acc[mt][nt][r]);
            }
}

// ---------------- fallback GEMM (fp32 inputs, in-kernel convert) ----------------
#define BM 128
#define BN 64
#define LDA 72

__global__ __launch_bounds__(256)
void gemm_f32(const float* __restrict__ x, const float* __restrict__ w,
              unsigned short* __restrict__ h)
{
    __shared__ unsigned short As2[BM][LDA];
    __shared__ unsigned short Bs2[BN][LDA];

    const int t = threadIdx.x, lane = t & 63, wave = t >> 6;
    const int wm = wave >> 1, wn = wave & 1;
    const int l15 = lane & 15, lq = lane >> 4;
    const int xcd = blockIdx.x & 7;
    const int loc = blockIdx.x >> 3;
    const int m0 = (xcd * 64 + (loc >> 3)) * BM;
    const int n0 = (loc & 7) * BN;

    floatx4 acc[4][2];
    #pragma unroll
    for (int i = 0; i < 4; i++)
        #pragma unroll
        for (int j = 0; j < 2; j++) acc[i][j] = (floatx4){0.f, 0.f, 0.f, 0.f};

    for (int kb = 0; kb < FEAT; kb += 64) {
        #pragma unroll
        for (int p = 0; p < 8; p++) {
            int idx = p * 256 + t, r = idx >> 4, cv = (idx & 15) << 2;
            float4 v = *(const float4*)&x[(m0 + r) * FEAT + kb + cv];
            ushort4 b4 = {f2bf(v.x), f2bf(v.y), f2bf(v.z), f2bf(v.w)};
            *(ushort4*)&As2[r][cv] = b4;
        }
        #pragma unroll
        for (int p = 0; p < 4; p++) {
            int idx = p * 256 + t, r = idx >> 4, cv = (idx & 15) << 2;
            float4 v = *(const float4*)&w[(n0 + r) * FEAT + kb + cv];
            ushort4 b4 = {f2bf(v.x), f2bf(v.y), f2bf(v.z), f2bf(v.w)};
            *(ushort4*)&Bs2[r][cv] = b4;
        }
        __syncthreads();
        #pragma unroll
        for (int kk = 0; kk < 2; kk++) {
            short8 af[4], bf[2];
            #pragma unroll
            for (int mt = 0; mt < 4; mt++)
                af[mt] = *(const short8*)&As2[wm * 64 + mt * 16 + l15][kk * 32 + lq * 8];
            #pragma unroll
            for (int nt = 0; nt < 2; nt++)
                bf[nt] = *(const short8*)&Bs2[wn * 32 + nt * 16 + l15][kk * 32 + lq * 8];
            #pragma unroll
            for (int mt = 0; mt < 4; mt++)
                #pragma unroll
                for (int nt = 0; nt < 2; nt++)
                    acc[mt][nt] = __builtin_amdgcn_mfma_f32_16x16x32_bf16(
                        af[mt], bf[nt], acc[mt][nt], 0, 0, 0);
        }
        __syncthreads();
    }
    #pragma unroll
    for (int mt = 0; mt < 4; mt++)
        #pragma unroll
        for (int nt = 0; nt < 2; nt++)
            #pragma unroll
            for (int r = 0; r < 4; r++) {
                int orow = m0 + wm * 64 + mt * 16 + lq * 4 + r;
                int ocol = n0 + wn * 32 + nt * 16 + l15;
                h[orow * EMB + ocol] = f2bf(acc[mt][nt][r]);
            }
}

// ---------------- one wave per row: batched independent gathers (round-0 proven) ----------------
__global__ __launch_bounds__(256)
void rowsum(const unsigned short* __restrict__ h, const int* __restrict__ cnt,
            const uintx2* __restrict__ ebuf, float* __restrict__ out)
{
    const int r    = blockIdx.x * 4 + (threadIdx.x >> 6);
    const int lane = threadIdx.x & 63;
    int deg = cnt[r];
    if (deg > CAP) deg = CAP;
    const int base = r * CAP;

    int   c_l = 0;
    float v_l = 0.f;
    if (lane < deg) {
        uintx2 ev = ebuf[base + lane];
        c_l = (int)ev.x;
        v_l = __uint_as_float(ev.y);
    }

    float acc[8] = {0.f,0.f,0.f,0.f,0.f,0.f,0.f,0.f};
    for (int i0 = 0; i0 < deg; i0 += 8) {
        uint4 hv[8]; float vv[8];
        int nn = deg - i0; if (nn > 8) nn = 8;
        #pragma unroll
        for (int j = 0; j < 8; j++) {
            if (j < nn) {
                int c = __shfl(c_l, i0 + j, 64);
                vv[j] = __shfl(v_l, i0 + j, 64);
                hv[j] = *(const uint4*)&h[(size_t)c * EMB + lane * 8];
            }
        }
        #pragma unroll
        for (int j = 0; j < 8; j++) {
            if (j < nn) {
                float v = vv[j];
                acc[0] += v * bf2f_lo(hv[j].x); acc[1] += v * bf2f_hi(hv[j].x);
                acc[2] += v * bf2f_lo(hv[j].y); acc[3] += v * bf2f_hi(hv[j].y);
                acc[4] += v * bf2f_lo(hv[j].z); acc[5] += v * bf2f_hi(hv[j].z);
                acc[6] += v * bf2f_lo(hv[j].w); acc[7] += v * bf2f_hi(hv[j].w);
            }
        }
    }
    floatx4* o = (floatx4*)&out[(size_t)r * EMB + lane * 8];
    floatx4 o0; o0.x = acc[0]; o0.y = acc[1]; o0.z = acc[2]; o0.w = acc[3];
    floatx4 o1; o1.x = acc[4]; o1.y = acc[5]; o1.z = acc[6]; o1.w = acc[7];
    __builtin_nontemporal_store(o0, o);
    __builtin_nontemporal_store(o1, o + 1);
}

// ---------------- last-resort: edge-parallel atomic scatter ----------------
__global__ __launch_bounds__(128)
void scatter_atomic(const int* __restrict__ row, const int* __restrict__ col,
                    const float* __restrict__ vals, const unsigned short* __restrict__ h,
                    float* __restrict__ out)
{
    int e = blockIdx.x;
    int r = row[e], c = col[e];
    float v = vals[e];
    int f = threadIdx.x * 4;
    uint2 hv = *(const uint2*)&h[c * EMB + f];
    float* o = &out[r * EMB + f];
    atomicAdd(o + 0, v * bf2f_lo(hv.x));
    atomicAdd(o + 1, v * bf2f_hi(hv.x));
    atomicAdd(o + 2, v * bf2f_lo(hv.y));
    atomicAdd(o + 3, v * bf2f_hi(hv.y));
}

extern "C" void kernel_launch(void* const* d_in, const int* in_sizes, int n_in,
                              void* d_out, int out_size, void* d_ws, size_t ws_size,
                              hipStream_t stream) {
    const float* x    = (const float*)d_in[0];
    const float* w    = (const float*)d_in[1];
    const int*   row  = (const int*)d_in[2];
    const int*   col  = (const int*)d_in[3];
    const float* vals = (const float*)d_in[4];
    float* out = (float*)d_out;
    char* ws = (char*)d_ws;

    const size_t SZ_WB  = (size_t)EMB * FEAT * 2;           //    524,288
    const size_t SZ_H   = (size_t)N_NODES * EMB * 2;        // 67,108,864
    const size_t SZ_CNT = (size_t)N_NODES * 4;              //    262,144
    const size_t SZ_E   = (size_t)N_NODES * CAP * 8;        // 33,554,432
    const size_t NEED_FAST = SZ_WB + SZ_H + SZ_CNT + SZ_E;  // ~96.9 MB
    const size_t NEED_BIN  = SZ_H + SZ_CNT + SZ_E;          // ~96.4 MB

    if (ws_size >= NEED_FAST) {
        unsigned short* wb = (unsigned short*)ws;
        unsigned short* h  = (unsigned short*)(ws + SZ_WB);
        int*    cnt  = (int*)(ws + SZ_WB + SZ_H);
        uintx2* ebuf = (uintx2*)(ws + SZ_WB + SZ_H + SZ_CNT);

        prep<<<dim3(128), dim3(256), 0, stream>>>(w, wb, cnt);
        fill_edges<<<dim3(N_EDGES / 256), dim3(256), 0, stream>>>(row, col, vals, cnt, ebuf);
        gemm_fused<<<dim3(2048), dim3(512), 0, stream>>>(x, wb, h);
        rowsum<<<dim3(N_NODES / 4), dim3(256), 0, stream>>>(h, cnt, ebuf, out);
    } else if (ws_size >= NEED_BIN) {
        unsigned short* h = (unsigned short*)ws;
        int*    cnt  = (int*)(ws + SZ_H);
        uintx2* ebuf = (uintx2*)(ws + SZ_H + SZ_CNT);

        gemm_f32<<<dim3(4096), dim3(256), 0, stream>>>(x, w, h);
        (void)hipMemsetAsync(cnt, 0, SZ_CNT, stream);
        fill_edges<<<dim3(N_EDGES / 256), dim3(256), 0, stream>>>(row, col, vals, cnt, ebuf);
        rowsum<<<dim3(N_NODES / 4), dim3(256), 0, stream>>>(h, cnt, ebuf, out);
    } else {
        unsigned short* h = (unsigned short*)ws;
        gemm_f32<<<dim3(4096), dim3(256), 0, stream>>>(x, w, h);
        (void)hipMemsetAsync(out, 0, (size_t)out_size * sizeof(float), stream);
        scatter_atomic<<<dim3(N_EDGES), dim3(128), 0, stream>>>(row, col, vals, h, out);
    }
}

// Round 8
// 369.811 us; speedup vs baseline: 1.1424x; 1.1424x over previous
//
#include <hip/hip_runtime.h>
#include <stdint.h>

// FusedGCNLayer: out = segment_sum(vals * (x @ W^T)[col], row)
// N=65536, E=524288, F=EMB=512.
// Budget model: fixed harness overhead ~145us; kernel-sum is the target.
// ROUND 7 (resubmitted unchanged after infra failure): single-variable fix vs round 6 —
// __launch_bounds__(512,8) forced a ~64-VGPR cap -> ~130MB/dispatch scratch spill
// (WRITE_SIZE 196MB vs 64MB of h). Drop the min-waves arg entirely; let the
// allocator take ~90-100 VGPR, zero spill.
// Pipeline: (1) prep: conv w->bf16 + zero cnt
//           (2) fill_edges: bin edges by dest row (~35us)
//           (3) gemm_fused BM=64 x BN=256, 40KB LDS, XCD-paired swizzle
//           (4) rowsum: one wave/row batched gathers (~99us @ 4.1TB/s gather wall)

#define N_NODES 65536
#define N_EDGES 524288
#define FEAT    512
#define EMB     512
#define CAP     64

typedef short  short8  __attribute__((ext_vector_type(8)));
typedef float  floatx4 __attribute__((ext_vector_type(4)));
typedef unsigned int uintx2 __attribute__((ext_vector_type(2)));

__device__ __forceinline__ unsigned short f2bf(float f) {
    unsigned int u = __float_as_uint(f);
    u += 0x7FFFu + ((u >> 16) & 1u);   // RNE
    return (unsigned short)(u >> 16);
}
__device__ __forceinline__ float bf2f_lo(unsigned int u){ return __uint_as_float(u << 16); }
__device__ __forceinline__ float bf2f_hi(unsigned int u){ return __uint_as_float(u & 0xffff0000u); }

typedef __attribute__((address_space(1))) const void* gas_vp;
typedef __attribute__((address_space(3))) void*       las_vp;
#define GLDS16(g, l) __builtin_amdgcn_global_load_lds((gas_vp)(const void*)(g), (las_vp)(void*)(l), 16, 0, 0)

// ---------------- prep: convert w (0.5 MB) to bf16 + zero cnt, one dispatch ----------------
__global__ __launch_bounds__(256)
void prep(const float* __restrict__ w, unsigned short* __restrict__ wb,
          int* __restrict__ cnt)
{
    size_t i = (size_t)blockIdx.x * 256 + threadIdx.x;   // 128 blocks * 256 = 32768 threads
    size_t j = i * 8;
    floatx4 a = *(const floatx4*)&w[j];
    floatx4 b = *(const floatx4*)&w[j + 4];
    ushort4 lo, hi;
    lo.x = f2bf(a.x); lo.y = f2bf(a.y); lo.z = f2bf(a.z); lo.w = f2bf(a.w);
    hi.x = f2bf(b.x); hi.y = f2bf(b.y); hi.z = f2bf(b.z); hi.w = f2bf(b.w);
    *(ushort4*)&wb[j]     = lo;
    *(ushort4*)&wb[j + 4] = hi;
    int2 z; z.x = 0; z.y = 0;
    *(int2*)&cnt[i * 2] = z;   // 65536 ints
}

// ---------------- bin edges by destination row (round-0 proven shape) ----------------
__global__ __launch_bounds__(256)
void fill_edges(const int* __restrict__ row, const int* __restrict__ col,
                const float* __restrict__ vals, int* __restrict__ cnt,
                uintx2* __restrict__ ebuf)
{
    int e = blockIdx.x * 256 + threadIdx.x;
    int   r = __builtin_nontemporal_load(&row[e]);
    int   c = __builtin_nontemporal_load(&col[e]);
    float v = __builtin_nontemporal_load(&vals[e]);
    int slot = atomicAdd(&cnt[r], 1);
    if (slot < CAP) {
        uintx2 ev; ev.x = (unsigned)c; ev.y = __float_as_uint(v);
        ebuf[r * CAP + slot] = ev;
    }
}

// ---------------- fused GEMM: BM=64 x BN=256, 40KB LDS, NO VGPR cap ----------------
// 512 threads = 8 waves; wave w owns output cols [n0 + w*32, n0 + w*32 + 32).
// A (x tile): fp32 global -> regs -> f2bf -> swizzled ds_write.
// B (wb):     global_load_lds width-16, pre-swizzled source, linear LDS dest.
// XCD-pairing swizzle: both n-tiles of one m land on the same XCD's L2.
__global__ __launch_bounds__(512)
void gemm_fused(const float* __restrict__ x, const unsigned short* __restrict__ wb,
                unsigned short* __restrict__ h)
{
    __shared__ unsigned short As[64 * 64];    //  8 KB
    __shared__ unsigned short Bs[256 * 64];   // 32 KB

    const int bid = blockIdx.x;
    const int lid = (bid & 7) * 256 + (bid >> 3);   // 2048 % 8 == 0 (bijective)
    const int m0  = (lid >> 1) * 64;
    const int n0  = (lid & 1) * 256;

    const int t    = threadIdx.x;      // 0..511
    const int lane = t & 63;
    const int wave = t >> 6;           // 0..7 -> 32-col sub-block
    const int l15  = lane & 15;
    const int lq   = lane >> 4;

    const int r8 = t >> 3;             // 0..63 (staging row)
    const int c8 = t & 7;              // 16B chunk index

    floatx4 acc[4][2];
    #pragma unroll
    for (int i = 0; i < 4; i++)
        #pragma unroll
        for (int j = 0; j < 2; j++) acc[i][j] = (floatx4){0.f, 0.f, 0.f, 0.f};

    // prefetch K-step 0 of A into regs
    float4 xa, xb_;
    {
        const float* px = &x[(size_t)(m0 + r8) * FEAT + c8 * 8];
        xa  = *(const float4*)px;
        xb_ = *(const float4*)(px + 4);
    }

    for (int kb = 0; kb < FEAT; kb += 64) {
        // stage Bs: 256 w-rows [n0, n0+256), 64-wide K slab, pre-swizzled global source
        #pragma unroll
        for (int p = 0; p < 4; p++) {
            int brow = p * 64 + r8;
            int lc   = c8 ^ (r8 & 7);                 // brow&7 == r8&7 (p*64 % 8 == 0)
            GLDS16(&wb[(size_t)(n0 + brow) * FEAT + kb + lc * 8], &Bs[brow * 64 + c8 * 8]);
        }
        // convert prefetched A regs -> swizzled LDS write
        {
            short8 v;
            v[0] = (short)f2bf(xa.x);  v[1] = (short)f2bf(xa.y);
            v[2] = (short)f2bf(xa.z);  v[3] = (short)f2bf(xa.w);
            v[4] = (short)f2bf(xb_.x); v[5] = (short)f2bf(xb_.y);
            v[6] = (short)f2bf(xb_.z); v[7] = (short)f2bf(xb_.w);
            *(short8*)&As[r8 * 64 + (c8 ^ (r8 & 7)) * 8] = v;
        }
        __syncthreads();

        // issue next K-step's x loads; latency hides under MFMA phase
        if (kb + 64 < FEAT) {
            const float* px = &x[(size_t)(m0 + r8) * FEAT + (kb + 64) + c8 * 8];
            xa  = *(const float4*)px;
            xb_ = *(const float4*)(px + 4);
        }

        #pragma unroll
        for (int kk = 0; kk < 2; kk++) {
            short8 af[4], bfr[2];
            #pragma unroll
            for (int mt = 0; mt < 4; mt++) {
                int r  = mt * 16 + l15;
                int pc = (kk * 4 + lq) ^ (r & 7);
                af[mt] = *(const short8*)&As[r * 64 + pc * 8];
            }
            #pragma unroll
            for (int nt = 0; nt < 2; nt++) {
                int r  = wave * 32 + nt * 16 + l15;
                int pc = (kk * 4 + lq) ^ (r & 7);
                bfr[nt] = *(const short8*)&Bs[r * 64 + pc * 8];
            }
            #pragma unroll
            for (int mt = 0; mt < 4; mt++)
                #pragma unroll
                for (int nt = 0; nt < 2; nt++)
                    acc[mt][nt] = __builtin_amdgcn_mfma_f32_16x16x32_bf16(
                        af[mt], bfr[nt], acc[mt][nt], 0, 0, 0);
        }
        __syncthreads();
    }

    #pragma unroll
    for (int mt = 0; mt < 4; mt++)
        #pragma unroll
        for (int nt = 0; nt < 2; nt++)
            #pragma unroll
            for (int r = 0; r < 4; r++) {
                int orow = m0 + mt * 16 + lq * 4 + r;
                int ocol = n0 + wave * 32 + nt * 16 + l15;
                h[(size_t)orow * EMB + ocol] = f2bf(acc[mt][nt][r]);
            }
}

// ---------------- fallback GEMM (fp32 inputs, in-kernel convert) ----------------
#define BM 128
#define BN 64
#define LDA 72

__global__ __launch_bounds__(256)
void gemm_f32(const float* __restrict__ x, const float* __restrict__ w,
              unsigned short* __restrict__ h)
{
    __shared__ unsigned short As2[BM][LDA];
    __shared__ unsigned short Bs2[BN][LDA];

    const int t = threadIdx.x, lane = t & 63, wave = t >> 6;
    const int wm = wave >> 1, wn = wave & 1;
    const int l15 = lane & 15, lq = lane >> 4;
    const int xcd = blockIdx.x & 7;
    const int loc = blockIdx.x >> 3;
    const int m0 = (xcd * 64 + (loc >> 3)) * BM;
    const int n0 = (loc & 7) * BN;

    floatx4 acc[4][2];
    #pragma unroll
    for (int i = 0; i < 4; i++)
        #pragma unroll
        for (int j = 0; j < 2; j++) acc[i][j] = (floatx4){0.f, 0.f, 0.f, 0.f};

    for (int kb = 0; kb < FEAT; kb += 64) {
        #pragma unroll
        for (int p = 0; p < 8; p++) {
            int idx = p * 256 + t, r = idx >> 4, cv = (idx & 15) << 2;
            float4 v = *(const float4*)&x[(m0 + r) * FEAT + kb + cv];
            ushort4 b4 = {f2bf(v.x), f2bf(v.y), f2bf(v.z), f2bf(v.w)};
            *(ushort4*)&As2[r][cv] = b4;
        }
        #pragma unroll
        for (int p = 0; p < 4; p++) {
            int idx = p * 256 + t, r = idx >> 4, cv = (idx & 15) << 2;
            float4 v = *(const float4*)&w[(n0 + r) * FEAT + kb + cv];
            ushort4 b4 = {f2bf(v.x), f2bf(v.y), f2bf(v.z), f2bf(v.w)};
            *(ushort4*)&Bs2[r][cv] = b4;
        }
        __syncthreads();
        #pragma unroll
        for (int kk = 0; kk < 2; kk++) {
            short8 af[4], bf[2];
            #pragma unroll
            for (int mt = 0; mt < 4; mt++)
                af[mt] = *(const short8*)&As2[wm * 64 + mt * 16 + l15][kk * 32 + lq * 8];
            #pragma unroll
            for (int nt = 0; nt < 2; nt++)
                bf[nt] = *(const short8*)&Bs2[wn * 32 + nt * 16 + l15][kk * 32 + lq * 8];
            #pragma unroll
            for (int mt = 0; mt < 4; mt++)
                #pragma unroll
                for (int nt = 0; nt < 2; nt++)
                    acc[mt][nt] = __builtin_amdgcn_mfma_f32_16x16x32_bf16(
                        af[mt], bf[nt], acc[mt][nt], 0, 0, 0);
        }
        __syncthreads();
    }
    #pragma unroll
    for (int mt = 0; mt < 4; mt++)
        #pragma unroll
        for (int nt = 0; nt < 2; nt++)
            #pragma unroll
            for (int r = 0; r < 4; r++) {
                int orow = m0 + wm * 64 + mt * 16 + lq * 4 + r;
                int ocol = n0 + wn * 32 + nt * 16 + l15;
                h[orow * EMB + ocol] = f2bf(acc[mt][nt][r]);
            }
}

// ---------------- one wave per row: batched independent gathers (round-0 proven) ----------------
__global__ __launch_bounds__(256)
void rowsum(const unsigned short* __restrict__ h, const int* __restrict__ cnt,
            const uintx2* __restrict__ ebuf, float* __restrict__ out)
{
    const int r    = blockIdx.x * 4 + (threadIdx.x >> 6);
    const int lane = threadIdx.x & 63;
    int deg = cnt[r];
    if (deg > CAP) deg = CAP;
    const int base = r * CAP;

    int   c_l = 0;
    float v_l = 0.f;
    if (lane < deg) {
        uintx2 ev = ebuf[base + lane];
        c_l = (int)ev.x;
        v_l = __uint_as_float(ev.y);
    }

    float acc[8] = {0.f,0.f,0.f,0.f,0.f,0.f,0.f,0.f};
    for (int i0 = 0; i0 < deg; i0 += 8) {
        uint4 hv[8]; float vv[8];
        int nn = deg - i0; if (nn > 8) nn = 8;
        #pragma unroll
        for (int j = 0; j < 8; j++) {
            if (j < nn) {
                int c = __shfl(c_l, i0 + j, 64);
                vv[j] = __shfl(v_l, i0 + j, 64);
                hv[j] = *(const uint4*)&h[(size_t)c * EMB + lane * 8];
            }
        }
        #pragma unroll
        for (int j = 0; j < 8; j++) {
            if (j < nn) {
                float v = vv[j];
                acc[0] += v * bf2f_lo(hv[j].x); acc[1] += v * bf2f_hi(hv[j].x);
                acc[2] += v * bf2f_lo(hv[j].y); acc[3] += v * bf2f_hi(hv[j].y);
                acc[4] += v * bf2f_lo(hv[j].z); acc[5] += v * bf2f_hi(hv[j].z);
                acc[6] += v * bf2f_lo(hv[j].w); acc[7] += v * bf2f_hi(hv[j].w);
            }
        }
    }
    floatx4* o = (floatx4*)&out[(size_t)r * EMB + lane * 8];
    floatx4 o0; o0.x = acc[0]; o0.y = acc[1]; o0.z = acc[2]; o0.w = acc[3];
    floatx4 o1; o1.x = acc[4]; o1.y = acc[5]; o1.z = acc[6]; o1.w = acc[7];
    __builtin_nontemporal_store(o0, o);
    __builtin_nontemporal_store(o1, o + 1);
}

// ---------------- last-resort: edge-parallel atomic scatter ----------------
__global__ __launch_bounds__(128)
void scatter_atomic(const int* __restrict__ row, const int* __restrict__ col,
                    const float* __restrict__ vals, const unsigned short* __restrict__ h,
                    float* __restrict__ out)
{
    int e = blockIdx.x;
    int r = row[e], c = col[e];
    float v = vals[e];
    int f = threadIdx.x * 4;
    uint2 hv = *(const uint2*)&h[c * EMB + f];
    float* o = &out[r * EMB + f];
    atomicAdd(o + 0, v * bf2f_lo(hv.x));
    atomicAdd(o + 1, v * bf2f_hi(hv.x));
    atomicAdd(o + 2, v * bf2f_lo(hv.y));
    atomicAdd(o + 3, v * bf2f_hi(hv.y));
}

extern "C" void kernel_launch(void* const* d_in, const int* in_sizes, int n_in,
                              void* d_out, int out_size, void* d_ws, size_t ws_size,
                              hipStream_t stream) {
    const float* x    = (const float*)d_in[0];
    const float* w    = (const float*)d_in[1];
    const int*   row  = (const int*)d_in[2];
    const int*   col  = (const int*)d_in[3];
    const float* vals = (const float*)d_in[4];
    float* out = (float*)d_out;
    char* ws = (char*)d_ws;

    const size_t SZ_WB  = (size_t)EMB * FEAT * 2;           //    524,288
    const size_t SZ_H   = (size_t)N_NODES * EMB * 2;        // 67,108,864
    const size_t SZ_CNT = (size_t)N_NODES * 4;              //    262,144
    const size_t SZ_E   = (size_t)N_NODES * CAP * 8;        // 33,554,432
    const size_t NEED_FAST = SZ_WB + SZ_H + SZ_CNT + SZ_E;  // ~96.9 MB
    const size_t NEED_BIN  = SZ_H + SZ_CNT + SZ_E;          // ~96.4 MB

    if (ws_size >= NEED_FAST) {
        unsigned short* wb = (unsigned short*)ws;
        unsigned short* h  = (unsigned short*)(ws + SZ_WB);
        int*    cnt  = (int*)(ws + SZ_WB + SZ_H);
        uintx2* ebuf = (uintx2*)(ws + SZ_WB + SZ_H + SZ_CNT);

        prep<<<dim3(128), dim3(256), 0, stream>>>(w, wb, cnt);
        fill_edges<<<dim3(N_EDGES / 256), dim3(256), 0, stream>>>(row, col, vals, cnt, ebuf);
        gemm_fused<<<dim3(2048), dim3(512), 0, stream>>>(x, wb, h);
        rowsum<<<dim3(N_NODES / 4), dim3(256), 0, stream>>>(h, cnt, ebuf, out);
    } else if (ws_size >= NEED_BIN) {
        unsigned short* h = (unsigned short*)ws;
        int*    cnt  = (int*)(ws + SZ_H);
        uintx2* ebuf = (uintx2*)(ws + SZ_H + SZ_CNT);

        gemm_f32<<<dim3(4096), dim3(256), 0, stream>>>(x, w, h);
        (void)hipMemsetAsync(cnt, 0, SZ_CNT, stream);
        fill_edges<<<dim3(N_EDGES / 256), dim3(256), 0, stream>>>(row, col, vals, cnt, ebuf);
        rowsum<<<dim3(N_NODES / 4), dim3(256), 0, stream>>>(h, cnt, ebuf, out);
    } else {
        unsigned short* h = (unsigned short*)ws;
        gemm_f32<<<dim3(4096), dim3(256), 0, stream>>>(x, w, h);
        (void)hipMemsetAsync(out, 0, (size_t)out_size * sizeof(float), stream);
        scatter_atomic<<<dim3(N_EDGES), dim3(128), 0, stream>>>(row, col, vals, h, out);
    }
}